// Round 9
// baseline (1530.633 us; speedup 1.0000x reference)
//
#include <hip/hip_runtime.h>
#include <stdint.h>

#define HH 128
#define WW 128
#define CHN 16
#define NPIX (HH*WW)          // 16384 per batch
#define PLANE (CHN*NPIX)      // 262144 per batch
#define STEPS 64
#define TW 8
#define TH 8
#define W1P 52                // w1 LDS row pad (jg-stride 52%32=20 -> CF)
#define W2P 20                // w2 LDS row pad
#define CBP 52                // combS row pad (px-stride CF, 16B aligned)

__host__ __device__ __forceinline__ uint32_t rotl32_(uint32_t x, int d) {
  return (x << d) | (x >> (32 - d));
}

__host__ __device__ __forceinline__ void tf2x32(uint32_t k0, uint32_t k1,
                                                uint32_t x0, uint32_t x1,
                                                uint32_t* o0, uint32_t* o1) {
  uint32_t ks0 = k0, ks1 = k1, ks2 = k0 ^ k1 ^ 0x1BD11BDAu;
  x0 += ks0; x1 += ks1;
  x0 += x1; x1 = rotl32_(x1, 13); x1 ^= x0;
  x0 += x1; x1 = rotl32_(x1, 15); x1 ^= x0;
  x0 += x1; x1 = rotl32_(x1, 26); x1 ^= x0;
  x0 += x1; x1 = rotl32_(x1, 6);  x1 ^= x0;
  x0 += ks1; x1 += ks2 + 1u;
  x0 += x1; x1 = rotl32_(x1, 17); x1 ^= x0;
  x0 += x1; x1 = rotl32_(x1, 29); x1 ^= x0;
  x0 += x1; x1 = rotl32_(x1, 16); x1 ^= x0;
  x0 += x1; x1 = rotl32_(x1, 24); x1 ^= x0;
  x0 += ks2; x1 += ks0 + 2u;
  x0 += x1; x1 = rotl32_(x1, 13); x1 ^= x0;
  x0 += x1; x1 = rotl32_(x1, 15); x1 ^= x0;
  x0 += x1; x1 = rotl32_(x1, 26); x1 ^= x0;
  x0 += x1; x1 = rotl32_(x1, 6);  x1 ^= x0;
  x0 += ks0; x1 += ks1 + 3u;
  x0 += x1; x1 = rotl32_(x1, 17); x1 ^= x0;
  x0 += x1; x1 = rotl32_(x1, 29); x1 ^= x0;
  x0 += x1; x1 = rotl32_(x1, 16); x1 ^= x0;
  x0 += x1; x1 = rotl32_(x1, 24); x1 ^= x0;
  x0 += ks1; x1 += ks2 + 4u;
  x0 += x1; x1 = rotl32_(x1, 13); x1 ^= x0;
  x0 += x1; x1 = rotl32_(x1, 15); x1 ^= x0;
  x0 += x1; x1 = rotl32_(x1, 26); x1 ^= x0;
  x0 += x1; x1 = rotl32_(x1, 6);  x1 ^= x0;
  x0 += ks2; x1 += ks0 + 5u;
  *o0 = x0; *o1 = x1;
}

// --- prep: transpose w1 (48 x 128) -> w1t (128 x 48)
__global__ void prep_w1t(const float* __restrict__ w1, float* __restrict__ w1t) {
  int i = blockIdx.x * 256 + threadIdx.x;
  if (i < 48 * 128) {
    int j = i / 48, k = i % 48;
    w1t[i] = w1[k * 128 + j];
  }
}

// --- fused per-step kernel. 8x8 tile, 512 threads = 8 waves.
// Weights staged in LDS (broadcast reads, conflict-free via row pads).
// Conv: channel-split (wave w -> ch 2w,2w+1; lane = pixel).
// j-loop: lane = (jg=lane>>3, pxl=lane&7); pixel = (row wv, col pxl);
// each lane sums j = jg+8*jj (16 j's); 3-step shfl_xor butterfly reduces
// over jg; lane then writes channels 2jg,2jg+1 of its pixel.
template <int MASKED>
__global__ __launch_bounds__(512, 4) void nca_step(
    const float* __restrict__ xin, const float* __restrict__ plin,
    const float* __restrict__ pw, const float* __restrict__ w1t,
    const float* __restrict__ b1, const float* __restrict__ w2,
    float* __restrict__ xout, float* __restrict__ plout,
    uint32_t k0, uint32_t k1)
{
  __shared__ float xt[CHN][TH + 2][TW + 2];  // staged tile (masked in-place)
  __shared__ float Axt[TH + 4][TW + 4];      // prev x-tilde alpha, 12x12
  __shared__ float Lf[TH + 2][TW + 2];       // life, 10x10
  __shared__ float combS[64][CBP];           // per-pixel comb
  __shared__ float uLDS[64];                 // RNG gate
  __shared__ float w1L[128][W1P];            // w1t rows (48 used)
  __shared__ float w2L[128][W2P];            // w2 rows (16 used)
  __shared__ float b1L[128];

  const int tid = threadIdx.x;
  const int blk = blockIdx.x;
  const int b  = blk >> 8;
  const int oh = ((blk >> 4) & 15) * TH;
  const int ow = (blk & 15) * TW;
  const float* xb = xin + (size_t)b * PLANE;

  // ---- phase 1: all global loads up front (weights + tile + alpha halo)
  for (int i = tid; i < (128 * 48) / 4; i += 512) {
    float4 v = ((const float4*)w1t)[i];
    int j = (4 * i) / 48, k = (4 * i) % 48;
    *(float4*)&w1L[j][k] = v;
  }
  for (int i = tid; i < (128 * 16) / 4; i += 512) {
    float4 v = ((const float4*)w2)[i];
    int j = (4 * i) / 16, c = (4 * i) % 16;
    *(float4*)&w2L[j][c] = v;
  }
  if (tid < 128) b1L[tid] = b1[tid];

  if (MASKED) {
    const float* ax = xb + 3 * NPIX;
    for (int i = tid; i < (TH + 4) * (TW + 4); i += 512) {
      int r = i / (TW + 4), c = i % (TW + 4);
      int gh = oh + r - 2, gw = ow + c - 2;
      Axt[r][c] = (gh >= 0 && gh < HH && gw >= 0 && gw < WW)
                      ? ax[gh * WW + gw] : 0.f;
    }
  }
  for (int i = tid; i < CHN * (TH + 2) * (TW + 2); i += 512) {
    int c  = i / ((TH + 2) * (TW + 2));
    int r  = (i / (TW + 2)) % (TH + 2);
    int cc = i % (TW + 2);
    int gh = oh + r - 1, gw = ow + cc - 1;
    xt[c][r][cc] = (gh >= 0 && gh < HH && gw >= 0 && gw < WW)
                       ? xb[(c * HH + gh) * WW + gw] : 0.f;
  }
  __syncthreads();

  // ---- phase 2 (masked only): life = (mp3(Axt)>0.1) & (plin>0.5); mask xt
  if (MASKED) {
    const float* pl = plin + b * NPIX;
    for (int i = tid; i < (TH + 2) * (TW + 2); i += 512) {
      int r = i / (TW + 2), c = i % (TW + 2);
      int gh = oh + r - 1, gw = ow + c - 1;
      float life = 0.f;
      if (gh >= 0 && gh < HH && gw >= 0 && gw < WW) {
        float m = Axt[r][c];
        m = fmaxf(m, Axt[r][c + 1]);     m = fmaxf(m, Axt[r][c + 2]);
        m = fmaxf(m, Axt[r + 1][c]);     m = fmaxf(m, Axt[r + 1][c + 1]);
        m = fmaxf(m, Axt[r + 1][c + 2]); m = fmaxf(m, Axt[r + 2][c]);
        m = fmaxf(m, Axt[r + 2][c + 1]); m = fmaxf(m, Axt[r + 2][c + 2]);
        if (m > 0.1f && pl[gh * WW + gw] > 0.5f) life = 1.f;
      }
      Lf[r][c] = life;
    }
    __syncthreads();
    for (int i = tid; i < CHN * (TH + 2) * (TW + 2); i += 512) {
      int c  = i / ((TH + 2) * (TW + 2));
      int rc = i % ((TH + 2) * (TW + 2));
      int r = rc / (TW + 2), cc = rc % (TW + 2);
      xt[c][r][cc] *= Lf[r][cc];
    }
    __syncthreads();
  }

  const int wv   = __builtin_amdgcn_readfirstlane((int)threadIdx.x) >> 6;
  const int lane = tid & 63;

  // ---- conv, channel-split: wave w -> channels 2w,2w+1; lane = pixel
  {
    const int pr = lane >> 3, pc = lane & 7;
    const int cA = 2 * wv, cB = 2 * wv + 1;
    float nA[9], nB[9];
    #pragma unroll
    for (int dy = 0; dy < 3; ++dy)
      #pragma unroll
      for (int dx = 0; dx < 3; ++dx) {
        nA[dy * 3 + dx] = xt[cA][pr + dy][pc + dx];
        nB[dy * 3 + dx] = xt[cB][pr + dy][pc + dx];
      }
    float pA0 = 0.f, pA1 = 0.f, pB0 = 0.f, pB1 = 0.f;
    #pragma unroll
    for (int i = 0; i < 9; ++i) {
      pA0 = fmaf(pw[(2 * cA) * 9 + i],     nA[i], pA0);
      pA1 = fmaf(pw[(2 * cA + 1) * 9 + i], nA[i], pA1);
      pB0 = fmaf(pw[(2 * cB) * 9 + i],     nB[i], pB0);
      pB1 = fmaf(pw[(2 * cB + 1) * 9 + i], nB[i], pB1);
    }
    combS[lane][cA] = nA[4];
    combS[lane][cB] = nB[4];
    combS[lane][16 + 2 * cA] = pA0;
    combS[lane][17 + 2 * cA] = pA1;
    combS[lane][16 + 2 * cB] = pB0;
    combS[lane][17 + 2 * cB] = pB1;
    if (wv == 1) {   // cB == 3: alpha channel -> prelife
      float m = nB[0];
      #pragma unroll
      for (int i = 1; i < 9; ++i) m = fmaxf(m, nB[i]);
      plout[b * NPIX + (oh + pr) * WW + (ow + pc)] = (m > 0.1f) ? 1.f : 0.f;
    }
  }
  __syncthreads();

  // wave 0: RNG gate for all 64 pixels (overlaps other waves' j-loops)
  if (wv == 0) {
    const int gr = (oh + (lane >> 3)) * WW + ow + (lane & 7);
    uint32_t o0, o1;
    tf2x32(k0, k1, 0u, (uint32_t)(b * NPIX + gr), &o0, &o1);
    const uint32_t bits = o0 ^ o1;
    uLDS[lane] = (((bits >> 31) == 0u) && (combS[lane][3] > 0.1f)) ? 1.f : 0.f;
  }

  // ---- j-loop: lane (jg,pxl), pixel = (row wv, col pxl), j = jg + 8*jj
  const int pxl = lane & 7, jg = lane >> 3;
  const int px = wv * 8 + pxl;

  float comb[48];
  {
    const float* cr = &combS[px][0];
    #pragma unroll
    for (int q = 0; q < 12; ++q) {
      float4 v = *(const float4*)(cr + 4 * q);
      comb[4 * q] = v.x; comb[4 * q + 1] = v.y;
      comb[4 * q + 2] = v.z; comb[4 * q + 3] = v.w;
    }
  }
  #pragma unroll
  for (int k = 0; k < 48; ++k) asm volatile("" : "+v"(comb[k]));

  float delta[16];
  #pragma unroll
  for (int c = 0; c < 16; ++c) delta[c] = 0.f;
  #pragma unroll
  for (int jj = 0; jj < 16; jj += 2) {
    const int ja = jg + 8 * jj, jb = ja + 8;
    const float* wa = &w1L[ja][0];
    const float* wb = &w1L[jb][0];
    float ha = b1L[ja], hb = b1L[jb];
    #pragma unroll
    for (int q = 0; q < 12; ++q) {
      const float4 a = *(const float4*)(wa + 4 * q);
      const float4 bq = *(const float4*)(wb + 4 * q);
      const float c0 = comb[4 * q], c1 = comb[4 * q + 1];
      const float c2 = comb[4 * q + 2], c3 = comb[4 * q + 3];
      ha = fmaf(c0, a.x, ha);  ha = fmaf(c1, a.y, ha);
      ha = fmaf(c2, a.z, ha);  ha = fmaf(c3, a.w, ha);
      hb = fmaf(c0, bq.x, hb); hb = fmaf(c1, bq.y, hb);
      hb = fmaf(c2, bq.z, hb); hb = fmaf(c3, bq.w, hb);
    }
    ha = fmaxf(ha, 0.f); hb = fmaxf(hb, 0.f);
    const float* va = &w2L[ja][0];
    const float* vb = &w2L[jb][0];
    #pragma unroll
    for (int q = 0; q < 4; ++q) {
      const float4 a = *(const float4*)(va + 4 * q);
      const float4 bq = *(const float4*)(vb + 4 * q);
      delta[4 * q]     = fmaf(ha, a.x, fmaf(hb, bq.x, delta[4 * q]));
      delta[4 * q + 1] = fmaf(ha, a.y, fmaf(hb, bq.y, delta[4 * q + 1]));
      delta[4 * q + 2] = fmaf(ha, a.z, fmaf(hb, bq.z, delta[4 * q + 2]));
      delta[4 * q + 3] = fmaf(ha, a.w, fmaf(hb, bq.w, delta[4 * q + 3]));
    }
  }

  // ---- in-register butterfly reduce over jg (lane bits 3,4,5)
  #pragma unroll
  for (int c = 0; c < 16; ++c) delta[c] += __shfl_xor(delta[c], 8, 64);
  #pragma unroll
  for (int c = 0; c < 16; ++c) delta[c] += __shfl_xor(delta[c], 16, 64);
  #pragma unroll
  for (int c = 0; c < 16; ++c) delta[c] += __shfl_xor(delta[c], 32, 64);

  __syncthreads();   // uLDS ready

  const float u = uLDS[px];
  const int gidx = (oh + wv) * WW + (ow + pxl);
  float* qb = xout + (size_t)b * PLANE;
  const int c0 = 2 * jg;
  qb[c0 * NPIX + gidx]       = fmaf(delta[c0], u, comb[c0]);
  qb[(c0 + 1) * NPIX + gidx] = fmaf(delta[c0 + 1], u, comb[c0 + 1]);
}

// --- final: out = x-tilde_63 * (mp3(x-tilde_63 alpha)>0.1 & prelife_63)
// Pixel (oh+pr, ow+pc) window in Axt coords: rows pr+1..pr+3 (R7-proven).
__global__ __launch_bounds__(256, 2) void nca_fin(
    const float* __restrict__ xl, const float* __restrict__ pl,
    float* __restrict__ out)
{
  __shared__ float Axt[TH + 4][TW + 4];
  const int tid = threadIdx.x;
  const int blk = blockIdx.x;
  const int b  = blk >> 8;
  const int oh = ((blk >> 4) & 15) * TH;
  const int ow = (blk & 15) * TW;
  const float* ax = xl + (size_t)b * PLANE + 3 * NPIX;
  for (int i = tid; i < (TH + 4) * (TW + 4); i += 256) {
    int r = i / (TW + 4), c = i % (TW + 4);
    int gh = oh + r - 2, gw = ow + c - 2;
    Axt[r][c] = (gh >= 0 && gh < HH && gw >= 0 && gw < WW)
                    ? ax[gh * WW + gw] : 0.f;
  }
  __syncthreads();
  const int wv = tid >> 6, lane = tid & 63;
  const int pr = lane >> 3, pc = lane & 7;
  const int gidx = (oh + pr) * WW + (ow + pc);
  float m = Axt[pr + 1][pc + 1];
  #pragma unroll
  for (int dy = 0; dy < 3; ++dy)
    #pragma unroll
    for (int dx = 0; dx < 3; ++dx)
      m = fmaxf(m, Axt[pr + 1 + dy][pc + 1 + dx]);
  const float lf = (m > 0.1f && pl[b * NPIX + gidx] > 0.5f) ? 1.f : 0.f;
  const float* qb = xl + (size_t)b * PLANE;
  float* ob = out + (size_t)b * PLANE;
  #pragma unroll
  for (int c2 = 0; c2 < 4; ++c2) {
    const int c = wv * 4 + c2;
    ob[c * NPIX + gidx] = qb[c * NPIX + gidx] * lf;
  }
}

extern "C" void kernel_launch(void* const* d_in, const int* in_sizes, int n_in,
                              void* d_out, int out_size, void* d_ws, size_t ws_size,
                              hipStream_t stream) {
  (void)in_sizes; (void)n_in; (void)out_size; (void)ws_size;
  const float* x  = (const float*)d_in[0];
  const float* pw = (const float*)d_in[1];
  const float* w1 = (const float*)d_in[2];
  const float* b1 = (const float*)d_in[3];
  const float* w2 = (const float*)d_in[4];

  float* out = (float*)d_out;
  float* ws  = (float*)d_ws;
  float* xb0 = ws;
  float* xb1 = ws + 2 * PLANE;
  float* pb0 = ws + 4 * PLANE;
  float* pb1 = ws + 4 * PLANE + 2 * NPIX;
  float* w1t = ws + 4 * PLANE + 4 * NPIX;

  prep_w1t<<<(48 * 128 + 255) / 256, 256, 0, stream>>>(w1, w1t);

  uint32_t key0[STEPS], key1[STEPS];
  for (uint32_t s = 0; s < STEPS; ++s)
    tf2x32(0u, 42u, 0u, s, &key0[s], &key1[s]);   // split(key(42)) partitionable

  float* xbuf[2] = { xb0, xb1 };
  float* pbuf[2] = { pb0, pb1 };
  nca_step<0><<<dim3(512), dim3(512), 0, stream>>>(
      x, nullptr, pw, w1t, b1, w2, xbuf[0], pbuf[0], key0[0], key1[0]);
  for (int s = 1; s < STEPS; ++s) {
    nca_step<1><<<dim3(512), dim3(512), 0, stream>>>(
        xbuf[(s - 1) & 1], pbuf[(s - 1) & 1], pw, w1t, b1, w2,
        xbuf[s & 1], pbuf[s & 1], key0[s], key1[s]);
  }
  const int lf = (STEPS - 1) & 1;
  nca_fin<<<dim3(512), dim3(256), 0, stream>>>(xbuf[lf], pbuf[lf], out);
}

// Round 10
// 1298.749 us; speedup vs baseline: 1.1785x; 1.1785x over previous
//
#include <hip/hip_runtime.h>
#include <stdint.h>

#define HH 128
#define WW 128
#define CHN 16
#define NPIX (HH*WW)          // 16384 per batch
#define PLANE (CHN*NPIX)      // 262144 per batch
#define STEPS 64
#define TW 8
#define TH 8

#define AS1 __attribute__((address_space(1)))
#define AS3 __attribute__((address_space(3)))

__device__ __forceinline__ void dma4(const float* g, float* l) {
  __builtin_amdgcn_global_load_lds((const AS1 float*)g, (AS3 float*)l, 4, 0, 0);
}

__host__ __device__ __forceinline__ uint32_t rotl32_(uint32_t x, int d) {
  return (x << d) | (x >> (32 - d));
}

__host__ __device__ __forceinline__ void tf2x32(uint32_t k0, uint32_t k1,
                                                uint32_t x0, uint32_t x1,
                                                uint32_t* o0, uint32_t* o1) {
  uint32_t ks0 = k0, ks1 = k1, ks2 = k0 ^ k1 ^ 0x1BD11BDAu;
  x0 += ks0; x1 += ks1;
  x0 += x1; x1 = rotl32_(x1, 13); x1 ^= x0;
  x0 += x1; x1 = rotl32_(x1, 15); x1 ^= x0;
  x0 += x1; x1 = rotl32_(x1, 26); x1 ^= x0;
  x0 += x1; x1 = rotl32_(x1, 6);  x1 ^= x0;
  x0 += ks1; x1 += ks2 + 1u;
  x0 += x1; x1 = rotl32_(x1, 17); x1 ^= x0;
  x0 += x1; x1 = rotl32_(x1, 29); x1 ^= x0;
  x0 += x1; x1 = rotl32_(x1, 16); x1 ^= x0;
  x0 += x1; x1 = rotl32_(x1, 24); x1 ^= x0;
  x0 += ks2; x1 += ks0 + 2u;
  x0 += x1; x1 = rotl32_(x1, 13); x1 ^= x0;
  x0 += x1; x1 = rotl32_(x1, 15); x1 ^= x0;
  x0 += x1; x1 = rotl32_(x1, 26); x1 ^= x0;
  x0 += x1; x1 = rotl32_(x1, 6);  x1 ^= x0;
  x0 += ks0; x1 += ks1 + 3u;
  x0 += x1; x1 = rotl32_(x1, 17); x1 ^= x0;
  x0 += x1; x1 = rotl32_(x1, 29); x1 ^= x0;
  x0 += x1; x1 = rotl32_(x1, 16); x1 ^= x0;
  x0 += x1; x1 = rotl32_(x1, 24); x1 ^= x0;
  x0 += ks1; x1 += ks2 + 4u;
  x0 += x1; x1 = rotl32_(x1, 13); x1 ^= x0;
  x0 += x1; x1 = rotl32_(x1, 15); x1 ^= x0;
  x0 += x1; x1 = rotl32_(x1, 26); x1 ^= x0;
  x0 += x1; x1 = rotl32_(x1, 6);  x1 ^= x0;
  x0 += ks2; x1 += ks0 + 5u;
  *o0 = x0; *o1 = x1;
}

// --- prep: transpose w1 (48 x 128) -> w1t (128 x 48); zero the DMA pad word
__global__ void prep_w1t(const float* __restrict__ w1, float* __restrict__ w1t,
                         float* __restrict__ zpad) {
  int i = blockIdx.x * 256 + threadIdx.x;
  if (i < 48 * 128) {
    int j = i / 48, k = i % 48;
    w1t[i] = w1[k * 128 + j];
  }
  if (blockIdx.x == 0 && threadIdx.x < 64) zpad[threadIdx.x] = 0.f;
}

// --- fused per-step kernel. 8x8 tile, 512 threads = 8 waves. R8 core +
// global_load_lds DMA staging (zpad redirect for OOB) + LDS prelife + early RNG.
template <int MASKED>
__global__ __launch_bounds__(512, 4) void nca_step(
    const float* __restrict__ xin, const float* __restrict__ plin,
    const float* __restrict__ pw, const float* __restrict__ w1t,
    const float* __restrict__ b1, const float* __restrict__ w2,
    const float* __restrict__ zpad,
    float* __restrict__ xout, float* __restrict__ plout,
    uint32_t k0, uint32_t k1)
{
  __shared__ float xtL[CHN * 100];           // [c][10][10] linear (DMA dest)
  __shared__ float AxtL[144];                // [12][12] linear (DMA dest)
  __shared__ float plL[100];                 // prelife 10x10 (DMA dest)
  __shared__ float Lf[100];                  // life 10x10
  __shared__ float combS[64][49];            // per-pixel comb (49: CF, proven)
  __shared__ uint32_t uBits[64];             // RNG bits (computed early)
  __shared__ float dbuf[8][64][17];          // 8-way reduce (proven)

  const int tid = threadIdx.x;
  const int blk = blockIdx.x;
  const int b  = blk >> 8;
  const int oh = ((blk >> 4) & 15) * TH;
  const int ow = (blk & 15) * TW;
  const float* xb = xin + (size_t)b * PLANE;

  // ---- phase 1: issue ALL staging as direct-to-LDS DMA (linear dests)
  if (MASKED) {
    const float* ax = xb + 3 * NPIX;
    if (tid < 144) {
      int r = tid / 12, c = tid % 12;
      int gh = oh + r - 2, gw = ow + c - 2;
      const float* g = (gh >= 0 && gh < HH && gw >= 0 && gw < WW)
                           ? &ax[gh * WW + gw] : zpad;
      dma4(g, &AxtL[tid]);
    }
    const float* pl = plin + b * NPIX;
    if (tid < 100) {
      int r = tid / 10, c = tid % 10;
      int gh = oh + r - 1, gw = ow + c - 1;
      const float* g = (gh >= 0 && gh < HH && gw >= 0 && gw < WW)
                           ? &pl[gh * WW + gw] : zpad;
      dma4(g, &plL[tid]);
    }
  }
  for (int i = tid; i < CHN * 100; i += 512) {
    int c = i / 100, rem = i % 100;
    int r = rem / 10, cc = rem % 10;
    int gh = oh + r - 1, gw = ow + cc - 1;
    const float* g = (gh >= 0 && gh < HH && gw >= 0 && gw < WW)
                         ? &xb[(c * HH + gh) * WW + gw] : zpad;
    dma4(g, &xtL[i]);
  }

  const int wv   = __builtin_amdgcn_readfirstlane((int)threadIdx.x) >> 6;
  const int lane = tid & 63;

  // RNG bits now, overlapped with the DMA latency (alpha gate applied later)
  if (wv == 0) {
    const int gr = (oh + (lane >> 3)) * WW + ow + (lane & 7);
    uint32_t o0, o1;
    tf2x32(k0, k1, 0u, (uint32_t)(b * NPIX + gr), &o0, &o1);
    uBits[lane] = o0 ^ o1;
  }
  __syncthreads();   // drains DMA (vmcnt) + uBits

  // ---- phase 2 (masked): life = (mp3(Axt)>0.1) & (plL>0.5); then mask xt
  if (MASKED) {
    if (tid < 100) {
      int r = tid / 10, c = tid % 10;
      float m = AxtL[r * 12 + c];
      m = fmaxf(m, AxtL[r * 12 + c + 1]);        m = fmaxf(m, AxtL[r * 12 + c + 2]);
      m = fmaxf(m, AxtL[(r + 1) * 12 + c]);      m = fmaxf(m, AxtL[(r + 1) * 12 + c + 1]);
      m = fmaxf(m, AxtL[(r + 1) * 12 + c + 2]);  m = fmaxf(m, AxtL[(r + 2) * 12 + c]);
      m = fmaxf(m, AxtL[(r + 2) * 12 + c + 1]);  m = fmaxf(m, AxtL[(r + 2) * 12 + c + 2]);
      Lf[tid] = (m > 0.1f && plL[tid] > 0.5f) ? 1.f : 0.f;
    }
    __syncthreads();
    for (int i = tid; i < CHN * 100; i += 512)
      xtL[i] *= Lf[i % 100];
    __syncthreads();
  }

  // ---- conv, channel-split: wave w -> channels 2w,2w+1; lane = pixel
  {
    const int pr = lane >> 3, pc = lane & 7;
    const int cA = 2 * wv, cB = 2 * wv + 1;
    float nA[9], nB[9];
    #pragma unroll
    for (int dy = 0; dy < 3; ++dy)
      #pragma unroll
      for (int dx = 0; dx < 3; ++dx) {
        nA[dy * 3 + dx] = xtL[cA * 100 + (pr + dy) * 10 + (pc + dx)];
        nB[dy * 3 + dx] = xtL[cB * 100 + (pr + dy) * 10 + (pc + dx)];
      }
    float pA0 = 0.f, pA1 = 0.f, pB0 = 0.f, pB1 = 0.f;
    #pragma unroll
    for (int i = 0; i < 9; ++i) {
      pA0 = fmaf(pw[(2 * cA) * 9 + i],     nA[i], pA0);
      pA1 = fmaf(pw[(2 * cA + 1) * 9 + i], nA[i], pA1);
      pB0 = fmaf(pw[(2 * cB) * 9 + i],     nB[i], pB0);
      pB1 = fmaf(pw[(2 * cB + 1) * 9 + i], nB[i], pB1);
    }
    combS[lane][cA] = nA[4];
    combS[lane][cB] = nB[4];
    combS[lane][16 + 2 * cA] = pA0;
    combS[lane][17 + 2 * cA] = pA1;
    combS[lane][16 + 2 * cB] = pB0;
    combS[lane][17 + 2 * cB] = pB1;
    if (wv == 1) {   // cB == 3: alpha channel -> prelife
      float m = nB[0];
      #pragma unroll
      for (int i = 1; i < 9; ++i) m = fmaxf(m, nB[i]);
      plout[b * NPIX + (oh + pr) * WW + (ow + pc)] = (m > 0.1f) ? 1.f : 0.f;
    }
  }
  __syncthreads();

  // ---- j-loop: wave w owns j in [16w,16w+16); lane = pixel; scalar weights
  const int jbase = wv * 16;
  float comb[48];
  {
    const float* cr = &combS[lane][0];
    #pragma unroll
    for (int q = 0; q < 12; ++q) {
      float4 v = *(const float4*)(cr + 4 * q);
      comb[4 * q] = v.x; comb[4 * q + 1] = v.y;
      comb[4 * q + 2] = v.z; comb[4 * q + 3] = v.w;
    }
  }
  #pragma unroll
  for (int k = 0; k < 48; ++k) asm volatile("" : "+v"(comb[k]));

  float delta[16];
  #pragma unroll
  for (int c = 0; c < 16; ++c) delta[c] = 0.f;
  for (int jj = 0; jj < 16; jj += 2) {
    const int j0 = jbase + jj;
    const float* wr0 = w1t + j0 * 48;
    const float* wr1 = wr0 + 48;
    float h0 = b1[j0], h1 = b1[j0 + 1];
    #pragma unroll
    for (int k = 0; k < 48; ++k) {
      h0 = fmaf(comb[k], wr0[k], h0);
      h1 = fmaf(comb[k], wr1[k], h1);
    }
    h0 = fmaxf(h0, 0.f); h1 = fmaxf(h1, 0.f);
    const float* w20 = w2 + j0 * 16;
    #pragma unroll
    for (int c = 0; c < 16; ++c)
      delta[c] = fmaf(h0, w20[c], fmaf(h1, w20[16 + c], delta[c]));
  }

  // ---- 8-way reduce; each wave then owns 2 output channels
  #pragma unroll
  for (int c = 0; c < 16; ++c) dbuf[wv][lane][c] = delta[c];
  __syncthreads();

  const float u = (((uBits[lane] >> 31) == 0u) && (comb[3] > 0.1f)) ? 1.f : 0.f;
  const int gidx = (oh + (lane >> 3)) * WW + (ow + (lane & 7));
  float* qb = xout + (size_t)b * PLANE;
  #pragma unroll
  for (int c2 = 0; c2 < 2; ++c2) {
    const int c = 2 * wv + c2;
    float s = dbuf[0][lane][c];
    #pragma unroll
    for (int t = 1; t < 8; ++t) s += dbuf[t][lane][c];
    qb[c * NPIX + gidx] = fmaf(s, u, comb[c]);
  }
}

// --- final: out = x-tilde_63 * (mp3(x-tilde_63 alpha)>0.1 & prelife_63)
// Pixel (oh+pr, ow+pc) window in Axt coords: rows pr+1..pr+3 (R7-proven).
__global__ __launch_bounds__(256, 2) void nca_fin(
    const float* __restrict__ xl, const float* __restrict__ pl,
    float* __restrict__ out)
{
  __shared__ float Axt[TH + 4][TW + 4];
  const int tid = threadIdx.x;
  const int blk = blockIdx.x;
  const int b  = blk >> 8;
  const int oh = ((blk >> 4) & 15) * TH;
  const int ow = (blk & 15) * TW;
  const float* ax = xl + (size_t)b * PLANE + 3 * NPIX;
  for (int i = tid; i < (TH + 4) * (TW + 4); i += 256) {
    int r = i / (TW + 4), c = i % (TW + 4);
    int gh = oh + r - 2, gw = ow + c - 2;
    Axt[r][c] = (gh >= 0 && gh < HH && gw >= 0 && gw < WW)
                    ? ax[gh * WW + gw] : 0.f;
  }
  __syncthreads();
  const int wv = tid >> 6, lane = tid & 63;
  const int pr = lane >> 3, pc = lane & 7;
  const int gidx = (oh + pr) * WW + (ow + pc);
  float m = Axt[pr + 1][pc + 1];
  #pragma unroll
  for (int dy = 0; dy < 3; ++dy)
    #pragma unroll
    for (int dx = 0; dx < 3; ++dx)
      m = fmaxf(m, Axt[pr + 1 + dy][pc + 1 + dx]);
  const float lf = (m > 0.1f && pl[b * NPIX + gidx] > 0.5f) ? 1.f : 0.f;
  const float* qb = xl + (size_t)b * PLANE;
  float* ob = out + (size_t)b * PLANE;
  #pragma unroll
  for (int c2 = 0; c2 < 4; ++c2) {
    const int c = wv * 4 + c2;
    ob[c * NPIX + gidx] = qb[c * NPIX + gidx] * lf;
  }
}

extern "C" void kernel_launch(void* const* d_in, const int* in_sizes, int n_in,
                              void* d_out, int out_size, void* d_ws, size_t ws_size,
                              hipStream_t stream) {
  (void)in_sizes; (void)n_in; (void)out_size; (void)ws_size;
  const float* x  = (const float*)d_in[0];
  const float* pw = (const float*)d_in[1];
  const float* w1 = (const float*)d_in[2];
  const float* b1 = (const float*)d_in[3];
  const float* w2 = (const float*)d_in[4];

  float* out = (float*)d_out;
  float* ws  = (float*)d_ws;
  float* xb0 = ws;
  float* xb1 = ws + 2 * PLANE;
  float* pb0 = ws + 4 * PLANE;
  float* pb1 = ws + 4 * PLANE + 2 * NPIX;
  float* w1t = ws + 4 * PLANE + 4 * NPIX;
  float* zpad = w1t + 48 * 128;

  prep_w1t<<<(48 * 128 + 255) / 256, 256, 0, stream>>>(w1, w1t, zpad);

  uint32_t key0[STEPS], key1[STEPS];
  for (uint32_t s = 0; s < STEPS; ++s)
    tf2x32(0u, 42u, 0u, s, &key0[s], &key1[s]);   // split(key(42)) partitionable

  float* xbuf[2] = { xb0, xb1 };
  float* pbuf[2] = { pb0, pb1 };
  nca_step<0><<<dim3(512), dim3(512), 0, stream>>>(
      x, nullptr, pw, w1t, b1, w2, zpad, xbuf[0], pbuf[0], key0[0], key1[0]);
  for (int s = 1; s < STEPS; ++s) {
    nca_step<1><<<dim3(512), dim3(512), 0, stream>>>(
        xbuf[(s - 1) & 1], pbuf[(s - 1) & 1], pw, w1t, b1, w2, zpad,
        xbuf[s & 1], pbuf[s & 1], key0[s], key1[s]);
  }
  const int lf = (STEPS - 1) & 1;
  nca_fin<<<dim3(512), dim3(256), 0, stream>>>(xbuf[lf], pbuf[lf], out);
}